// Round 10
// baseline (102.231 us; speedup 1.0000x reference)
//
#include <hip/hip_runtime.h>
#include <stdint.h>

// out[t][n] = (sum_k q8(x[t]/sq)[k] * w8[n][k]) * a_scale[t] * (wclip[n]/127) + bias[n]
#define T_TOK 32768
#define NIN   1024
#define NOUT  1024
#define BM    64      // tokens per tile; block owns 2 tiles (128 tokens)
#define NTHR  512     // 8 waves: 0-3 producers (quant), 4-7 consumers (GEMM)

typedef int   v4i  __attribute__((ext_vector_type(4)));
typedef int   v16i __attribute__((ext_vector_type(16)));
typedef float v4f  __attribute__((ext_vector_type(4)));

#define MFMA_I8(a, b, c) __builtin_amdgcn_mfma_i32_32x32x32_i8(a, b, c, 0, 0, 0)

// ---------------------------------------------------------------------------
// K0: repack weight (int32 [NOUT][NIN]) into MFMA fragment order:
//   16B chunk (nt,ks,lane) holds W[nt*32+(lane&31)][ks*32+(lane>>5)*16 .. +15]
// so a B-frag load is one coalesced global_load_dwordx4 at base + lane*16.
// (r3/r7/r8-verified)
// ---------------------------------------------------------------------------
__global__ __launch_bounds__(256) void repack_w_frag(const int* __restrict__ w,
                                                     uint32_t* __restrict__ wf) {
  const int gid  = blockIdx.x * 256 + threadIdx.x;
  const int lane = gid & 63;
  const int ks   = (gid >> 6) & 31;
  const int nt   = gid >> 11;
  const int n    = nt * 32 + (lane & 31);
  const int kb   = ks * 32 + (lane >> 5) * 16;
  const int* src = w + (size_t)n * NIN + kb;
  uint32_t d[4];
#pragma unroll
  for (int q = 0; q < 4; ++q) {
    const int4 v = ((const int4*)src)[q];
    d[q] = (uint32_t)(v.x & 0xff) | ((uint32_t)(v.y & 0xff) << 8) |
           ((uint32_t)(v.z & 0xff) << 16) | ((uint32_t)(v.w & 0xff) << 24);
  }
  ((uint4*)wf)[gid] = make_uint4(d[0], d[1], d[2], d[3]);
}

// ---------------------------------------------------------------------------
// K1: persistent producer/consumer fused kernel.
// Waves 0-3 quantize tile i+1 into the spare LDS buffer while waves 4-7 run
// tile i's GEMM (B streamed from L2, depth-2 register ring) and epilogue.
// State is SPLIT across waves (r4's failure was every wave holding acc AND
// x-stage): producers hold no accs, consumers hold no x-state -> ~208 regs
// -> 2 waves/SIMD, exactly one resident 8-wave block per CU.
// LDS A layout (r3-verified): token tl, k-step ks, 16B-half h stored at chunk
// ((tl>>5)*32+ks)*64 + (((tl&31)+32h) ^ (ks&7)); read at lane^(ks&7).
// ---------------------------------------------------------------------------
__global__ __launch_bounds__(NTHR, 2) void fused_pc(
    const float* __restrict__ x,      // [T_TOK][NIN]
    const uint8_t* __restrict__ wf,   // fragment-ordered weight, 1 MB
    const float* __restrict__ sq,     // [NIN]
    const float* __restrict__ wclip,  // [NOUT]
    const float* __restrict__ bias,   // [NOUT]
    float* __restrict__ out)          // [T_TOK][NOUT]
{
  __shared__ __align__(16) uint8_t Af[2][BM * NIN];   // 2 x 64 KiB
  __shared__ float ascale_s[2][BM];

  const int tid  = threadIdx.x;
  const int lane = tid & 63;
  const int w    = tid >> 6;                 // 0..7
  const int bt0  = blockIdx.x * (2 * BM);    // grid 256 -> 1 block/CU

  const v4f* sq4 = (const v4f*)sq;

  auto make_rs = [&](v4f* rs) {
#pragma unroll
    for (int j = 0; j < 4; ++j) {
      const v4f s = sq4[j * 64 + lane];
      rs[j].x = __builtin_amdgcn_rcpf(s.x);
      rs[j].y = __builtin_amdgcn_rcpf(s.y);
      rs[j].z = __builtin_amdgcn_rcpf(s.z);
      rs[j].w = __builtin_amdgcn_rcpf(s.w);
    }
  };

  auto quant_store = [&](int buf, int tl, const v4f* v, float ia) {
    const int mt = tl >> 5;
#pragma unroll
    for (int j = 0; j < 4; ++j) {
      const int q0 = (int)rintf(fminf(fmaxf(v[j].x * ia, -127.f), 127.f));
      const int q1 = (int)rintf(fminf(fmaxf(v[j].y * ia, -127.f), 127.f));
      const int q2 = (int)rintf(fminf(fmaxf(v[j].z * ia, -127.f), 127.f));
      const int q3 = (int)rintf(fminf(fmaxf(v[j].w * ia, -127.f), 127.f));
      const uint32_t d = (uint32_t)(q0 & 0xff) | ((uint32_t)(q1 & 0xff) << 8) |
                         ((uint32_t)(q2 & 0xff) << 16) | ((uint32_t)(q3 & 0xff) << 24);
      const int di   = j * 64 + lane;        // dword col 0..255
      const int ksw  = di >> 3;              // k-step 0..31
      const int hh   = (di >> 2) & 1;        // 16B half
      const int slot = (tl & 31) + 32 * hh;
      const int chunk = (mt * 32 + ksw) * 64 + (slot ^ (ksw & 7));
      *(uint32_t*)(&Af[buf][chunk * 16 + (di & 3) * 4]) = d;
    }
  };

  // two tokens per call: >=8KB of loads in flight so few waves still reach BW
  auto quant_pair = [&](int buf, int t0, int tl, const v4f* rs) {
    const v4f* xa = (const v4f*)(x + (size_t)(t0 + tl) * NIN);
    const v4f* xb = (const v4f*)(x + (size_t)(t0 + tl + 1) * NIN);
    v4f va[4], vb[4];
#pragma unroll
    for (int j = 0; j < 4; ++j) va[j] = __builtin_nontemporal_load(&xa[j * 64 + lane]);
#pragma unroll
    for (int j = 0; j < 4; ++j) vb[j] = __builtin_nontemporal_load(&xb[j * 64 + lane]);
    float ma = 0.f, mb = 0.f;
#pragma unroll
    for (int j = 0; j < 4; ++j) {
      va[j].x *= rs[j].x; va[j].y *= rs[j].y; va[j].z *= rs[j].z; va[j].w *= rs[j].w;
      vb[j].x *= rs[j].x; vb[j].y *= rs[j].y; vb[j].z *= rs[j].z; vb[j].w *= rs[j].w;
      ma = fmaxf(ma, fmaxf(fmaxf(fabsf(va[j].x), fabsf(va[j].y)),
                           fmaxf(fabsf(va[j].z), fabsf(va[j].w))));
      mb = fmaxf(mb, fmaxf(fmaxf(fabsf(vb[j].x), fabsf(vb[j].y)),
                           fmaxf(fabsf(vb[j].z), fabsf(vb[j].w))));
    }
#pragma unroll
    for (int off = 1; off < 64; off <<= 1) {
      ma = fmaxf(ma, __shfl_xor(ma, off));
      mb = fmaxf(mb, __shfl_xor(mb, off));
    }
    const float asa = fmaxf(ma * (1.f / 127.f), 1e-8f);
    const float asb = fmaxf(mb * (1.f / 127.f), 1e-8f);
    if (lane == 0) { ascale_s[buf][tl] = asa; ascale_s[buf][tl + 1] = asb; }
    quant_store(buf, tl,     va, __builtin_amdgcn_rcpf(asa));
    quant_store(buf, tl + 1, vb, __builtin_amdgcn_rcpf(asb));
  };

  // ---- consumer: GEMM + dequant + write for one 64-token tile --------------
  auto consumer_tile = [&](int buf, int t0g) {
    const int wc = w - 4;                    // 0..3
#pragma unroll
    for (int h = 0; h < 2; ++h) {            // two 512-col n-halves
      const uint8_t* Bb = wf + ((size_t)(h * 16 + wc * 4) << 15) + (size_t)lane * 16;
      auto ldB = [&](int ks, int nt) -> v4i {
        return *(const v4i*)(Bb + nt * 32768 + ks * 1024);
      };
      auto ldA = [&](int mt, int ks) -> v4i {
        return *(const v4i*)(&Af[buf][(((mt * 32 + ks) * 64) + (lane ^ (ks & 7))) << 4]);
      };
      v4i Ba[4], Bo[4];
#pragma unroll
      for (int nt = 0; nt < 4; ++nt) { Ba[nt] = ldB(0, nt); Bo[nt] = ldB(1, nt); }
      v16i acc[2][4] = {};
      for (int ks = 0; ks < 32; ks += 2) {
        {
          const v4i a0 = ldA(0, ks), a1 = ldA(1, ks);
          __builtin_amdgcn_s_setprio(1);
#pragma unroll
          for (int nt = 0; nt < 4; ++nt) {
            acc[0][nt] = MFMA_I8(a0, Ba[nt], acc[0][nt]);
            acc[1][nt] = MFMA_I8(a1, Ba[nt], acc[1][nt]);
          }
          __builtin_amdgcn_s_setprio(0);
          if (ks + 2 < 32) {
#pragma unroll
            for (int nt = 0; nt < 4; ++nt) Ba[nt] = ldB(ks + 2, nt);
          }
        }
        {
          const v4i a0 = ldA(0, ks + 1), a1 = ldA(1, ks + 1);
          __builtin_amdgcn_s_setprio(1);
#pragma unroll
          for (int nt = 0; nt < 4; ++nt) {
            acc[0][nt] = MFMA_I8(a0, Bo[nt], acc[0][nt]);
            acc[1][nt] = MFMA_I8(a1, Bo[nt], acc[1][nt]);
          }
          __builtin_amdgcn_s_setprio(0);
          if (ks + 3 < 32) {
#pragma unroll
            for (int nt = 0; nt < 4; ++nt) Bo[nt] = ldB(ks + 3, nt);
          }
        }
      }
      // epilogue: C/D col = lane&31, row = (reg&3)+8*(reg>>2)+4*(lane>>5)
      const int hr = 4 * (lane >> 5);
#pragma unroll
      for (int mt = 0; mt < 2; ++mt) {
        float ascv[16];
#pragma unroll
        for (int reg = 0; reg < 16; ++reg)
          ascv[reg] = ascale_s[buf][mt * 32 + (reg & 3) + 8 * (reg >> 2) + hr];
#pragma unroll
        for (int nt = 0; nt < 4; ++nt) {
          const int n = h * 512 + wc * 128 + nt * 32 + (lane & 31);
          const float wsc = wclip[n] * (1.f / 127.f);
          const float bs  = bias[n];
#pragma unroll
          for (int reg = 0; reg < 16; ++reg) {
            const int r = t0g + mt * 32 + (reg & 3) + 8 * (reg >> 2) + hr;
            __builtin_nontemporal_store(
                (float)acc[mt][nt][reg] * ascv[reg] * wsc + bs,
                &out[(size_t)r * NOUT + n]);
          }
        }
      }
    }
  };

  // ---- prologue: ALL 8 waves quant tile 0 (8 tokens each) ------------------
  {
    v4f rs[4]; make_rs(rs);
#pragma unroll
    for (int p = 0; p < 4; ++p) quant_pair(0, bt0, w * 8 + p * 2, rs);
  }
  __syncthreads();

  // ---- super-step 0: producers quant tile1, consumers GEMM tile0 -----------
  if (w < 4) {
    v4f rs[4]; make_rs(rs);
#pragma unroll
    for (int p = 0; p < 8; ++p) quant_pair(1, bt0 + BM, w * 16 + p * 2, rs);
  } else {
    consumer_tile(0, bt0);
  }
  __syncthreads();

  // ---- super-step 1: consumers GEMM tile1 (producers done) -----------------
  if (w >= 4) consumer_tile(1, bt0 + BM);
}

// ---------------------------------------------------------------------------
extern "C" void kernel_launch(void* const* d_in, const int* in_sizes, int n_in,
                              void* d_out, int out_size, void* d_ws, size_t ws_size,
                              hipStream_t stream) {
  const float* x      = (const float*)d_in[0];
  const int*   weight = (const int*)d_in[1];
  const float* bias   = (const float*)d_in[2];
  const float* wclip  = (const float*)d_in[3];
  const float* sq     = (const float*)d_in[4];
  float* out = (float*)d_out;

  uint32_t* wfrag = (uint32_t*)d_ws;   // 1 MB fragment-ordered weight

  repack_w_frag<<<(NOUT * NIN / 16) / 256, 256, 0, stream>>>(weight, wfrag);
  fused_pc<<<T_TOK / (2 * BM), NTHR, 0, stream>>>(x, (const uint8_t*)wfrag,
                                                  sq, wclip, bias, out);
}

// Round 11
// 91.957 us; speedup vs baseline: 1.1117x; 1.1117x over previous
//
#include <hip/hip_runtime.h>
#include <stdint.h>

// out[t][n] = (sum_k q8(x[t]/sq)[k] * w8[n][k]) * a_scale[t] * (wclip[n]/127) + bias[n]
#define T_TOK 32768
#define NIN   1024
#define NOUT  1024

typedef int   v4i  __attribute__((ext_vector_type(4)));
typedef int   v16i __attribute__((ext_vector_type(16)));
typedef float v4f  __attribute__((ext_vector_type(4)));

#define MFMA_I8(a, b, c) __builtin_amdgcn_mfma_i32_32x32x32_i8(a, b, c, 0, 0, 0)

__device__ __forceinline__ void gload_lds16(const void* g, void* l) {
  __builtin_amdgcn_global_load_lds(
      (const __attribute__((address_space(1))) unsigned int*)g,
      (__attribute__((address_space(3))) unsigned int*)l, 16, 0, 0);
}

// Fragment layout (A and B): 16B chunk = (tile32*32 + ks)*64 + (row&31) + 32*h
// holding row's bytes k = ks*32 + h*16 .. +15. MFMA operand load for
// (tile32, ks) = one coalesced dwordx4 at base + lane*16. (r7/r8/r9-verified)

// ---------------------------------------------------------------------------
// K0: repack weight (int32 [NOUT][NIN]) into fragment order. (verified)
// ---------------------------------------------------------------------------
__global__ __launch_bounds__(256) void repack_w_frag(const int* __restrict__ w,
                                                     uint32_t* __restrict__ wf) {
  const int gid  = blockIdx.x * 256 + threadIdx.x;
  const int lane = gid & 63;
  const int ks   = (gid >> 6) & 31;
  const int nt   = gid >> 11;
  const int n    = nt * 32 + (lane & 31);
  const int kb   = ks * 32 + (lane >> 5) * 16;
  const int* src = w + (size_t)n * NIN + kb;
  uint32_t d[4];
#pragma unroll
  for (int q = 0; q < 4; ++q) {
    const int4 v = ((const int4*)src)[q];
    d[q] = (uint32_t)(v.x & 0xff) | ((uint32_t)(v.y & 0xff) << 8) |
           ((uint32_t)(v.z & 0xff) << 16) | ((uint32_t)(v.w & 0xff) << 24);
  }
  ((uint4*)wf)[gid] = make_uint4(d[0], d[1], d[2], d[3]);
}

// ---------------------------------------------------------------------------
// K1: quant (r9-verified, unchanged): coalesced x reads, swizzled LDS tile,
// coalesced fragment-ordered xq output.
// ---------------------------------------------------------------------------
__global__ __launch_bounds__(512) void quant2(const float* __restrict__ x,
                                              const float* __restrict__ sq,
                                              uint32_t* __restrict__ afw,
                                              float* __restrict__ asc) {
  __shared__ __align__(16) uint8_t Af[32 * NIN];   // 32 KiB

  const int tid  = threadIdx.x;
  const int lane = tid & 63;
  const int w    = tid >> 6;          // 0..7
  const int t0   = blockIdx.x * 32;

  {
    const v4f* sq4 = (const v4f*)sq;
    v4f rs[4];
#pragma unroll
    for (int j = 0; j < 4; ++j) {
      const v4f s = sq4[j * 64 + lane];
      rs[j].x = __builtin_amdgcn_rcpf(s.x);
      rs[j].y = __builtin_amdgcn_rcpf(s.y);
      rs[j].z = __builtin_amdgcn_rcpf(s.z);
      rs[j].w = __builtin_amdgcn_rcpf(s.w);
    }
#pragma unroll
    for (int i = 0; i < 4; ++i) {
      const int tl = w * 4 + i;                       // 0..31
      const v4f* xr = (const v4f*)(x + (size_t)(t0 + tl) * NIN);
      v4f v[4];
      float m = 0.f;
#pragma unroll
      for (int j = 0; j < 4; ++j) {
        v4f a = __builtin_nontemporal_load(&xr[j * 64 + lane]);
        a.x *= rs[j].x; a.y *= rs[j].y; a.z *= rs[j].z; a.w *= rs[j].w;
        v[j] = a;
        m = fmaxf(m, fmaxf(fmaxf(fabsf(a.x), fabsf(a.y)),
                           fmaxf(fabsf(a.z), fabsf(a.w))));
      }
#pragma unroll
      for (int off = 1; off < 64; off <<= 1) m = fmaxf(m, __shfl_xor(m, off));
      const float as = fmaxf(m * (1.f / 127.f), 1e-8f);
      if (lane == 0) asc[t0 + tl] = as;
      const float ia = __builtin_amdgcn_rcpf(as);
#pragma unroll
      for (int j = 0; j < 4; ++j) {
        const int q0 = (int)rintf(fminf(fmaxf(v[j].x * ia, -127.f), 127.f));
        const int q1 = (int)rintf(fminf(fmaxf(v[j].y * ia, -127.f), 127.f));
        const int q2 = (int)rintf(fminf(fmaxf(v[j].z * ia, -127.f), 127.f));
        const int q3 = (int)rintf(fminf(fmaxf(v[j].w * ia, -127.f), 127.f));
        const uint32_t d = (uint32_t)(q0 & 0xff) | ((uint32_t)(q1 & 0xff) << 8) |
                           ((uint32_t)(q2 & 0xff) << 16) | ((uint32_t)(q3 & 0xff) << 24);
        const int di   = j * 64 + lane;      // dword col 0..255
        const int ksw  = di >> 3;            // k-step 0..31
        const int h    = (di >> 2) & 1;      // 16B half
        const int slot = ((tl ^ (ksw & 7)) & 31) + 32 * h;
        *(uint32_t*)(&Af[(ksw * 64 + slot) * 16 + (di & 3) * 4]) = d;
      }
    }
  }
  __syncthreads();

  // output: 2048 chunks of 16B -> 4/thread, coalesced; un-XOR low-5 bits.
  v4i* dst = (v4i*)afw + (size_t)blockIdx.x * 2048;
#pragma unroll
  for (int p = 0; p < 4; ++p) {
    const int cg = p * 512 + tid;
    const int ks = cg >> 6;
    const int lc = (cg & ~31) | ((cg ^ (ks & 7)) & 31);
    __builtin_nontemporal_store(*(const v4i*)(&Af[lc * 16]), &dst[cg]);
  }
}

// ---------------------------------------------------------------------------
// K2: fragment GEMM, tile 128t x 256n, 512 thr / 8 waves -> 2 blocks/CU
// (16 waves/CU of TLP — the thing r9's 4-wave gemm lacked).
// Wave = 64t x 64n -> acc[2][2] = 64 AGPR (r3's proven 64-VGPR shape).
// A staged in LDS via global_load_lds in two 64KB K-halves (fragment order is
// lane-linear: no swizzle, conflict-free). B depth-2 ring from L2-resident wf.
// ---------------------------------------------------------------------------
__global__ __launch_bounds__(512, 4) void gemm3(
    const uint8_t* __restrict__ af,     // fragment-ordered xq, 32 MB
    const uint8_t* __restrict__ wf,     // fragment-ordered weight, 1 MB
    const float* __restrict__ asc,      // [T_TOK]
    const float* __restrict__ wclip,    // [NOUT]
    const float* __restrict__ bias,     // [NOUT]
    float* __restrict__ out)            // [T_TOK][NOUT]
{
  __shared__ __align__(16) uint8_t As[64 * 1024];   // one K-half of A tile

  const int g   = blockIdx.x;           // 1024
  const int xcd = g & 7;
  const int j   = g >> 3;               // 0..127
  const int T   = xcd * 32 + (j >> 2);  // t-tile 0..255 (n-siblings same XCD)
  const int nq  = j & 3;                // 256-col slice

  const int tid  = threadIdx.x;
  const int lane = tid & 63;
  const int w    = tid >> 6;            // 0..7
  const int wr   = w >> 2;              // 0..1  (64-token half)
  const int wc   = w & 3;               // 0..3  (64-col slice)

  const uint8_t* Abase = af + ((size_t)(T * 4) << 15);   // 128 KB tile
  const uint8_t* Bb = wf + ((size_t)(nq * 8 + wc * 2) << 15) + (size_t)lane * 16;

  auto stage_half = [&](int h) {
#pragma unroll
    for (int p = 0; p < 8; ++p) {
      const int off = p * 8192 + tid * 16;      // lane-linear 64 KB
      const int mt  = off >> 14;                // tile32 within block
      const int inr = off & 16383;
      gload_lds16(Abase + mt * 32768 + h * 16384 + inr, As + off);
    }
  };
  auto ldA = [&](int i, int ksl) -> v4i {       // i: wave's mt (0/1), ksl 0..15
    return *(const v4i*)(As + (wr * 2 + i) * 16384 + ksl * 1024 + lane * 16);
  };
  auto ldB = [&](int ks, int i) -> v4i {        // ks 0..31 global, i: nt (0/1)
    return *(const v4i*)(Bb + i * 32768 + ks * 1024);
  };

  v16i acc[2][2] = {};
  v4i Ba[2], Bo[2];

  stage_half(0);
  Ba[0] = ldB(0, 0); Ba[1] = ldB(0, 1);
  Bo[0] = ldB(1, 0); Bo[1] = ldB(1, 1);
  __syncthreads();                              // half 0 staged

#define KSTEP(BR, KSL, KN)                                                   \
  do {                                                                       \
    const v4i a0 = ldA(0, (KSL)), a1 = ldA(1, (KSL));                        \
    __builtin_amdgcn_s_setprio(1);                                           \
    acc[0][0] = MFMA_I8(a0, BR[0], acc[0][0]);                               \
    acc[0][1] = MFMA_I8(a0, BR[1], acc[0][1]);                               \
    acc[1][0] = MFMA_I8(a1, BR[0], acc[1][0]);                               \
    acc[1][1] = MFMA_I8(a1, BR[1], acc[1][1]);                               \
    __builtin_amdgcn_s_setprio(0);                                           \
    if ((KN) < 32) { BR[0] = ldB((KN), 0); BR[1] = ldB((KN), 1); }           \
  } while (0)

#pragma unroll
  for (int kp = 0; kp < 16; kp += 2) {          // half 0: ks = kp
    KSTEP(Ba, kp,     kp + 2);
    KSTEP(Bo, kp + 1, kp + 3);
  }
  __syncthreads();                              // all waves done reading h0
  stage_half(1);
  __syncthreads();                              // half 1 staged
#pragma unroll
  for (int kp = 0; kp < 16; kp += 2) {          // half 1: ks = 16 + kp
    KSTEP(Ba, kp,     16 + kp + 2);
    KSTEP(Bo, kp + 1, 16 + kp + 3);
  }
#undef KSTEP

  // epilogue: C/D col = lane&31 (n), row = (reg&3)+8*(reg>>2)+4*(lane>>5)
  const int hr = 4 * (lane >> 5);
#pragma unroll
  for (int i = 0; i < 2; ++i) {
    const int t0 = T * 128 + (wr * 2 + i) * 32;
    float ascv[16];
#pragma unroll
    for (int reg = 0; reg < 16; ++reg)
      ascv[reg] = asc[t0 + (reg & 3) + 8 * (reg >> 2) + hr];
#pragma unroll
    for (int jn = 0; jn < 2; ++jn) {
      const int n = nq * 256 + wc * 64 + jn * 32 + (lane & 31);
      const float wsc = wclip[n] * (1.f / 127.f);
      const float bs  = bias[n];
#pragma unroll
      for (int reg = 0; reg < 16; ++reg) {
        const int r = t0 + (reg & 3) + 8 * (reg >> 2) + hr;
        __builtin_nontemporal_store(
            (float)acc[i][jn][reg] * ascv[reg] * wsc + bs,
            &out[(size_t)r * NOUT + n]);
      }
    }
  }
}

// ---------------------------------------------------------------------------
extern "C" void kernel_launch(void* const* d_in, const int* in_sizes, int n_in,
                              void* d_out, int out_size, void* d_ws, size_t ws_size,
                              hipStream_t stream) {
  const float* x      = (const float*)d_in[0];
  const int*   weight = (const int*)d_in[1];
  const float* bias   = (const float*)d_in[2];
  const float* wclip  = (const float*)d_in[3];
  const float* sq     = (const float*)d_in[4];
  float* out = (float*)d_out;

  // ws: wf 1 MB | af (fragment xq) 32 MB | asc 128 KB
  uint8_t* ws = (uint8_t*)d_ws;
  uint32_t* wfrag = (uint32_t*)ws;
  uint32_t* afrag = (uint32_t*)(ws + (1u << 20));
  float*    ascp  = (float*)(ws + (1u << 20) + ((size_t)T_TOK * NIN));

  repack_w_frag<<<(NOUT * NIN / 16) / 256, 256, 0, stream>>>(weight, wfrag);
  quant2<<<T_TOK / 32, 512, 0, stream>>>(x, sq, afrag, ascp);
  gemm3<<<1024, 512, 0, stream>>>((const uint8_t*)afrag, (const uint8_t*)wfrag,
                                  ascp, wclip, bias, out);
}